// Round 6
// baseline (34.948 us; speedup 1.0000x reference)
//
#include <hip/hip_runtime.h>

// Product_50242527428657: out[b,o] = prod_k (x[b,k]*w[o,k] + 1) - 1 + bias[o]   (ALPHA==1)
// B=1024, IN=256, OUT=512, fp32. No fp32 MFMA -> vector-ALU kernel.
//
// Round-6:
//  - NO LDS staging at all: within a block each w element is read by exactly one thread
//    (threads partition col-group x k-split), so R5's w tile was a wasted LDS round-trip.
//    wv[4][4] hoisted to registers (1KB/thread, 64B-line-local -> L1 absorbs); xv from
//    global per chunk (16-lane broadcast groups, x fully L2-resident).
//  - Packed fp32 math (v_pk_fma_f32/v_pk_mul_f32): float4 components (x,y)/(z,w) are
//    native aligned VGPR pairs -> pack over k with zero pack-moves. Per (i,j,chunk):
//    2 pk_fma + 1 pk_mul + 2 mul = 10 cyc for 4 k vs 16 scalar. Main VALU 3.4 -> 2.1us.
//  - LDS = 16-way-k-split combine only (64KB, 32 b128/thread ~ 1.3us), ONE barrier.
//  - Geometry unchanged: grid (8,64)=512 blocks, 256 thr, 2 blocks/CU, per-thread
//    16 rows x 4 cols x 16 k. Live set ~ acc 64 + wv 64 + sched ~ 220 VGPR < 256.

#define BATCH 1024
#define IN    256
#define OUT   512

typedef float f32x2 __attribute__((ext_vector_type(2)));
typedef float f32x4 __attribute__((ext_vector_type(4)));

__global__ __launch_bounds__(256, 2) void product_kernel(
    const float* __restrict__ x, const float* __restrict__ w,
    const float* __restrict__ bias, float* __restrict__ out)
{
    __shared__ f32x4 part4[16 * 16 * 16];   // [s][r][c4] float4 = 64 KB (combine only)

    const int tid  = threadIdx.x;
    const int wid  = tid >> 6;        // wave 0..3
    const int lane = tid & 63;
    const int sbl  = lane >> 4;       // in-wave k-split 0..3
    const int l4   = lane & 15;       // col group: cols o0 + 4*l4 .. +3
    const int s    = wid * 4 + sbl;   // k-split 0..15: chunks [4s, 4s+4)

    const int o0 = blockIdx.x * 64;
    const int b0 = blockIdx.y * 16;

    const f32x4* x4g = (const f32x4*)x;   // [1024][64]
    const f32x4* w4g = (const f32x4*)w;   // [512][64]

    // ---- hoist the thread's entire w working set: 4 rows x 4 chunks = 1KB.
    //      Per (row): chunks 4s..4s+3 are one aligned 64B line -> 4 loads, 1 L2 line. ----
    f32x4 wv[4][4];
    #pragma unroll
    for (int j = 0; j < 4; ++j)
        #pragma unroll
        for (int p = 0; p < 4; ++p)
            wv[j][p] = w4g[(size_t)(o0 + 4 * l4 + j) * 64 + 4 * s + p];

    f32x4 acc[16];
    #pragma unroll
    for (int i = 0; i < 16; ++i) acc[i] = (f32x4)(1.0f);

    const f32x2 one2 = (f32x2)(1.0f);

    #pragma unroll 1                  // one chunk-generation of xv live at a time
    for (int p = 0; p < 4; ++p) {
        const int c = 4 * s + p;      // logical chunk for this thread

        #pragma unroll
        for (int i = 0; i < 16; ++i) {
            const f32x4 xv = x4g[(size_t)(b0 + i) * 64 + c];   // 16-lane broadcast, L2-hot
            const f32x2 xlo = __builtin_shufflevector(xv, xv, 0, 1);
            const f32x2 xhi = __builtin_shufflevector(xv, xv, 2, 3);
            #pragma unroll
            for (int j = 0; j < 4; ++j) {
                const f32x2 wlo = __builtin_shufflevector(wv[j][p], wv[j][p], 0, 1);
                const f32x2 whi = __builtin_shufflevector(wv[j][p], wv[j][p], 2, 3);
                const f32x2 t0 = __builtin_elementwise_fma(xlo, wlo, one2);  // v_pk_fma_f32
                const f32x2 t1 = __builtin_elementwise_fma(xhi, whi, one2);  // v_pk_fma_f32
                const f32x2 m  = t0 * t1;                                    // v_pk_mul_f32
                acc[i][j] *= m.x * m.y;
            }
        }
    }

    // ---- combine: 16 partials per output via LDS; single barrier in the kernel ----
    #pragma unroll
    for (int i = 0; i < 16; ++i)
        part4[(s * 16 + i) * 16 + l4] = acc[i];
    __syncthreads();

    // ---- epilogue: thread -> (row r, col-group c4); prod over s (fixed order) ----
    const int r  = tid >> 4;          // 0..15
    const int c4 = tid & 15;          // 0..15
    f32x4 pr = part4[r * 16 + c4];    // s = 0
    #pragma unroll
    for (int ss = 1; ss < 16; ++ss)
        pr *= part4[(ss * 16 + r) * 16 + c4];   // v_pk_mul_f32 x2

    const f32x4 bv = ((const f32x4*)bias)[(o0 >> 2) + c4];
    const f32x4 o  = pr - 1.0f + bv;
    ((f32x4*)out)[(size_t)(b0 + r) * (OUT / 4) + (o0 >> 2) + c4] = o;
}

extern "C" void kernel_launch(void* const* d_in, const int* in_sizes, int n_in,
                              void* d_out, int out_size, void* d_ws, size_t ws_size,
                              hipStream_t stream) {
    const float* x    = (const float*)d_in[0];   // (1024, 256)
    const float* wgt  = (const float*)d_in[1];   // (512, 256)
    const float* bias = (const float*)d_in[2];   // (512,)
    float* out        = (float*)d_out;           // (1024, 512)

    dim3 grid(OUT / 64, BATCH / 16);   // (8, 64) = 512 blocks
    dim3 block(256);
    product_kernel<<<grid, block, 0, stream>>>(x, wgt, bias, out);
}

// Round 7
// 21.541 us; speedup vs baseline: 1.6224x; 1.6224x over previous
//
#include <hip/hip_runtime.h>

// Product_50242527428657: out[b,o] = prod_k (x[b,k]*w[o,k] + 1) - 1 + bias[o]   (ALPHA==1)
// B=1024, IN=256, OUT=512, fp32. No fp32 MFMA -> vector-ALU kernel.
//
// Round-7: R6 hit guide rule #20 — wv[4][4] runtime-indexed by the unroll-1 loop var
// went to SCRATCH (VGPR=88, 32MB scratch writes, 57us). Fix: identical structure but
// every register-array access is static:
//  - w loads moved INSIDE the p-loop as 4 named scalars (runtime ADDRESS ok; only
//    register-array INDEXING scratches). 16 loads total, 64B-line-local -> L1-hot.
//  - acc[16] f32x4 only indexed by fully-unrolled i / component j.
//  - packed fp32 (v_pk_fma_f32 / v_pk_mul_f32) over the k dimension, zero pack-moves.
//  - no LDS staging (w is read by exactly one thread per block; x has no in-block
//    reuse across threads beyond the 16-lane broadcast the VMEM pipe gives free).
//  - LDS = 64KB combine buffer only; ONE barrier total.
// Geometry: grid (8,64)=512 blocks, 256 thr, 2 blocks/CU, per-thread 16r x 4c x 16k.

#define BATCH 1024
#define IN    256
#define OUT   512

typedef float f32x2 __attribute__((ext_vector_type(2)));
typedef float f32x4 __attribute__((ext_vector_type(4)));

__global__ __launch_bounds__(256, 2) void product_kernel(
    const float* __restrict__ x, const float* __restrict__ w,
    const float* __restrict__ bias, float* __restrict__ out)
{
    __shared__ f32x4 part4[16 * 16 * 16];   // [s][r][c4] = 64 KB (combine only)

    const int tid  = threadIdx.x;
    const int wid  = tid >> 6;        // wave 0..3
    const int lane = tid & 63;
    const int sbl  = lane >> 4;       // in-wave k-split 0..3
    const int l4   = lane & 15;       // col group: cols o0 + 4*l4 .. +3
    const int s    = wid * 4 + sbl;   // k-split 0..15: chunks [4s, 4s+4)

    const int o0 = blockIdx.x * 64;
    const int b0 = blockIdx.y * 16;

    const f32x4* x4g = (const f32x4*)x;   // [1024][64]
    const f32x4* w4g = (const f32x4*)w;   // [512][64]

    const size_t wrow = (size_t)(o0 + 4 * l4) * 64 + 4 * s;   // w base: row 4*l4, chunk 4s

    f32x4 acc[16];
    #pragma unroll
    for (int i = 0; i < 16; ++i) acc[i] = (f32x4)(1.0f);

    const f32x2 one2 = (f32x2)(1.0f);

    #pragma unroll 1                  // one generation live; all reg arrays static-indexed
    for (int p = 0; p < 4; ++p) {
        const int c = 4 * s + p;      // this thread's logical chunk

        // 4 named w chunks for this p (runtime address, static registers; L1-hot)
        const f32x4 wva = w4g[wrow + 0 * 64 + p];
        const f32x4 wvb = w4g[wrow + 1 * 64 + p];
        const f32x4 wvc = w4g[wrow + 2 * 64 + p];
        const f32x4 wvd = w4g[wrow + 3 * 64 + p];

        const f32x2 wa_lo = __builtin_shufflevector(wva, wva, 0, 1);
        const f32x2 wa_hi = __builtin_shufflevector(wva, wva, 2, 3);
        const f32x2 wb_lo = __builtin_shufflevector(wvb, wvb, 0, 1);
        const f32x2 wb_hi = __builtin_shufflevector(wvb, wvb, 2, 3);
        const f32x2 wc_lo = __builtin_shufflevector(wvc, wvc, 0, 1);
        const f32x2 wc_hi = __builtin_shufflevector(wvc, wvc, 2, 3);
        const f32x2 wd_lo = __builtin_shufflevector(wvd, wvd, 0, 1);
        const f32x2 wd_hi = __builtin_shufflevector(wvd, wvd, 2, 3);

        #pragma unroll
        for (int i = 0; i < 16; ++i) {
            const f32x4 xv  = x4g[(size_t)(b0 + i) * 64 + c];  // 16-lane broadcast, L2-hot
            const f32x2 xlo = __builtin_shufflevector(xv, xv, 0, 1);
            const f32x2 xhi = __builtin_shufflevector(xv, xv, 2, 3);

            f32x2 t0, t1, m;
            t0 = __builtin_elementwise_fma(xlo, wa_lo, one2);   // v_pk_fma_f32
            t1 = __builtin_elementwise_fma(xhi, wa_hi, one2);
            m  = t0 * t1;                                       // v_pk_mul_f32
            acc[i].x *= m.x * m.y;
            t0 = __builtin_elementwise_fma(xlo, wb_lo, one2);
            t1 = __builtin_elementwise_fma(xhi, wb_hi, one2);
            m  = t0 * t1;
            acc[i].y *= m.x * m.y;
            t0 = __builtin_elementwise_fma(xlo, wc_lo, one2);
            t1 = __builtin_elementwise_fma(xhi, wc_hi, one2);
            m  = t0 * t1;
            acc[i].z *= m.x * m.y;
            t0 = __builtin_elementwise_fma(xlo, wd_lo, one2);
            t1 = __builtin_elementwise_fma(xhi, wd_hi, one2);
            m  = t0 * t1;
            acc[i].w *= m.x * m.y;
        }
    }

    // ---- combine: 16 partials per output via LDS; single barrier in the kernel ----
    #pragma unroll
    for (int i = 0; i < 16; ++i)
        part4[(s * 16 + i) * 16 + l4] = acc[i];
    __syncthreads();

    // ---- epilogue: thread -> (row r, col-group c4); prod over s (fixed order) ----
    const int r  = tid >> 4;          // 0..15
    const int c4 = tid & 15;          // 0..15
    f32x4 pr = part4[r * 16 + c4];    // s = 0
    #pragma unroll
    for (int ss = 1; ss < 16; ++ss)
        pr *= part4[(ss * 16 + r) * 16 + c4];   // v_pk_mul_f32 x2

    const f32x4 bv = ((const f32x4*)bias)[(o0 >> 2) + c4];
    const f32x4 o  = pr - 1.0f + bv;
    ((f32x4*)out)[(size_t)(b0 + r) * (OUT / 4) + (o0 >> 2) + c4] = o;
}

extern "C" void kernel_launch(void* const* d_in, const int* in_sizes, int n_in,
                              void* d_out, int out_size, void* d_ws, size_t ws_size,
                              hipStream_t stream) {
    const float* x    = (const float*)d_in[0];   // (1024, 256)
    const float* wgt  = (const float*)d_in[1];   // (512, 256)
    const float* bias = (const float*)d_in[2];   // (512,)
    float* out        = (float*)d_out;           // (1024, 512)

    dim3 grid(OUT / 64, BATCH / 16);   // (8, 64) = 512 blocks
    dim3 block(256);
    product_kernel<<<grid, block, 0, stream>>>(x, wgt, bias, out);
}

// Round 8
// 18.995 us; speedup vs baseline: 1.8398x; 1.1340x over previous
//
#include <hip/hip_runtime.h>

// Product_50242527428657: out[b,o] = prod_k (x[b,k]*w[o,k] + 1) - 1 + bias[o]   (ALPHA==1)
// B=1024, IN=256, OUT=512, fp32. No fp32 MFMA -> vector-ALU kernel.
//
// Round-8 = Round-5 memory structure + packed fp32 math.
//  - R5 (14.04us, best): coalesced-stage w -> LDS (swizzled), x direct from L2,
//    LDS-only combine. R7 proved w-from-global is a 1KB-stride 64-line gather (-7.5us).
//  - Packed math over k: float4 (x,y)/(z,w) are native VGPR pairs -> v_pk_fma_f32 /
//    v_pk_mul_f32 with zero pack-moves. 5 instr/4k vs 8 scalar: VALU 3.4 -> 2.1us/CU.
//  - Rule #20: wv read from LDS inside the unroll-1 p-loop as 4 NAMED f32x4 (runtime
//    LDS address is fine; no runtime-indexed register arrays anywhere).
// Geometry: grid (8,64)=512 blocks, 256 thr, 2 blocks/CU (LDS 64KB), per-thread
// 16 rows x 4 cols x 16 k (k-split 16 via wid,sbl), 3 barriers total.

#define BATCH 1024
#define IN    256
#define OUT   512

typedef float f32x2 __attribute__((ext_vector_type(2)));
typedef float f32x4 __attribute__((ext_vector_type(4)));

__global__ __launch_bounds__(256, 2) void product_kernel(
    const float* __restrict__ x, const float* __restrict__ w,
    const float* __restrict__ bias, float* __restrict__ out)
{
    __shared__ f32x4 ws4[64 * 64];   // 64 KB: w rows o0..o0+63, phys chunk = c ^ ((row>>2)&7)

    const int tid  = threadIdx.x;
    const int wid  = tid >> 6;        // wave 0..3
    const int lane = tid & 63;
    const int sbl  = lane >> 4;       // in-wave k-split 0..3
    const int l4   = lane & 15;       // col group: cols o0 + 4*l4 .. +3
    const int s    = wid * 4 + sbl;   // k-split 0..15: chunks [4s, 4s+4)

    const int o0 = blockIdx.x * 64;
    const int b0 = blockIdx.y * 16;

    const f32x4* x4g = (const f32x4*)x;   // [1024][64]
    const f32x4* w4g = (const f32x4*)w;   // [512][64]

    // ---- stage w tile: wave writes whole rows; lane==chunk -> phys = lane ^ const
    //      is a permutation (conflict-free); global side fully coalesced (1KB/wave) ----
    #pragma unroll
    for (int it = 0; it < 16; ++it) {
        const int r = it * 4 + wid;                         // 0..63, wave-uniform
        ws4[r * 64 + (lane ^ ((r >> 2) & 7))] = w4g[(o0 + r) * 64 + lane];
    }
    __syncthreads();

    f32x4 acc[16];
    #pragma unroll
    for (int i = 0; i < 16; ++i) acc[i] = (f32x4)(1.0f);

    const int wsw = l4 & 7;           // ws swizzle for rows 4*l4+j (row>>2 == l4)
    const int wr  = 4 * l4 * 64;      // base of lane's 4 w rows
    const f32x2 one2 = (f32x2)(1.0f);

    #pragma unroll 1                  // one chunk-generation live; no runtime reg indexing
    for (int p = 0; p < 4; ++p) {
        const int c  = 4 * s + p;     // logical chunk for this thread
        const int cw = c ^ wsw;

        // 4 named w chunks from LDS (conflict-free: 64 lanes spread over 8 bank groups)
        const f32x4 wv0 = ws4[wr + 0 * 64 + cw];
        const f32x4 wv1 = ws4[wr + 1 * 64 + cw];
        const f32x4 wv2 = ws4[wr + 2 * 64 + cw];
        const f32x4 wv3 = ws4[wr + 3 * 64 + cw];

        const f32x2 w0lo = __builtin_shufflevector(wv0, wv0, 0, 1);
        const f32x2 w0hi = __builtin_shufflevector(wv0, wv0, 2, 3);
        const f32x2 w1lo = __builtin_shufflevector(wv1, wv1, 0, 1);
        const f32x2 w1hi = __builtin_shufflevector(wv1, wv1, 2, 3);
        const f32x2 w2lo = __builtin_shufflevector(wv2, wv2, 0, 1);
        const f32x2 w2hi = __builtin_shufflevector(wv2, wv2, 2, 3);
        const f32x2 w3lo = __builtin_shufflevector(wv3, wv3, 0, 1);
        const f32x2 w3hi = __builtin_shufflevector(wv3, wv3, 2, 3);

        #pragma unroll
        for (int i = 0; i < 16; ++i) {
            const f32x4 xv  = x4g[(size_t)(b0 + i) * 64 + c];  // 16-lane broadcast, L2-hot
            const f32x2 xlo = __builtin_shufflevector(xv, xv, 0, 1);
            const f32x2 xhi = __builtin_shufflevector(xv, xv, 2, 3);

            f32x2 t0, t1, m;
            t0 = __builtin_elementwise_fma(xlo, w0lo, one2);    // v_pk_fma_f32
            t1 = __builtin_elementwise_fma(xhi, w0hi, one2);
            m  = t0 * t1;                                       // v_pk_mul_f32
            acc[i].x *= m.x * m.y;
            t0 = __builtin_elementwise_fma(xlo, w1lo, one2);
            t1 = __builtin_elementwise_fma(xhi, w1hi, one2);
            m  = t0 * t1;
            acc[i].y *= m.x * m.y;
            t0 = __builtin_elementwise_fma(xlo, w2lo, one2);
            t1 = __builtin_elementwise_fma(xhi, w2hi, one2);
            m  = t0 * t1;
            acc[i].z *= m.x * m.y;
            t0 = __builtin_elementwise_fma(xlo, w3lo, one2);
            t1 = __builtin_elementwise_fma(xhi, w3hi, one2);
            m  = t0 * t1;
            acc[i].w *= m.x * m.y;
        }
    }

    // ---- combine: partials -> LDS (aliases ws4; all wv reads done), fixed order ----
    __syncthreads();
    f32x4* part4 = ws4;               // reinterpret as [16 s][16 r][16 c4] = 64 KB
    #pragma unroll
    for (int i = 0; i < 16; ++i)
        part4[(s * 16 + i) * 16 + l4] = acc[i];
    __syncthreads();

    // ---- epilogue: thread -> (row r, col-group c4); prod over s (fixed order) ----
    const int r  = tid >> 4;          // 0..15
    const int c4 = tid & 15;          // 0..15
    f32x4 pr = part4[r * 16 + c4];    // s = 0
    #pragma unroll
    for (int ss = 1; ss < 16; ++ss)
        pr *= part4[(ss * 16 + r) * 16 + c4];   // v_pk_mul_f32 x2

    const f32x4 bv = ((const f32x4*)bias)[(o0 >> 2) + c4];
    const f32x4 o  = pr - 1.0f + bv;
    ((f32x4*)out)[(size_t)(b0 + r) * (OUT / 4) + (o0 >> 2) + c4] = o;
}

extern "C" void kernel_launch(void* const* d_in, const int* in_sizes, int n_in,
                              void* d_out, int out_size, void* d_ws, size_t ws_size,
                              hipStream_t stream) {
    const float* x    = (const float*)d_in[0];   // (1024, 256)
    const float* wgt  = (const float*)d_in[1];   // (512, 256)
    const float* bias = (const float*)d_in[2];   // (512,)
    float* out        = (float*)d_out;           // (1024, 512)

    dim3 grid(OUT / 64, BATCH / 16);   // (8, 64) = 512 blocks
    dim3 block(256);
    product_kernel<<<grid, block, 0, stream>>>(x, wgt, bias, out);
}

// Round 9
// 13.835 us; speedup vs baseline: 2.5261x; 1.3730x over previous
//
#include <hip/hip_runtime.h>

// Product_50242527428657: out[b,o] = prod_k (x[b,k]*w[o,k] + 1) - 1 + bias[o]   (ALPHA==1)
// B=1024, IN=256, OUT=512, fp32. No fp32 MFMA -> vector-ALU kernel.
//
// Round-9 = exact revert to Round-5 (best measured: 14.04us).
// Why this structure is the roofline configuration:
//  - VALU floor: 2 ops/triple (fma, mul) x 1.34e8 triples = 3.4us/chip. Irreducible:
//    product-reduction can't use MFMA, no fp32 MFMA on CDNA4, and v_pk_fma_f32 has NO
//    throughput advantage (157.3 TF spec == scalar rate; R8 proved it regresses).
//  - w staged via LDS: coalesced 1KB/wave global reads + permutation-swizzled writes
//    (lane^const), conflict-free swizzled reads. R7 proved direct w reads are a
//    1KB-stride 64-line gather (+7.5us). Each w element: 1 global + 1 LDS wr + 1 LDS rd.
//  - x read direct from L2 (zero in-block reuse per element beyond the free 16-lane
//    broadcast; R4 proved LDS-staging x wastes LDS-pipe cycles).
//  - 16-way k-split, LDS-only combine (R3 proved shfl combine costs ~3.4us on LDS pipe).
//  - LDS pipe ~2.6us and VMEM ~1us overlap under VALU 3.4us across 8 waves/CU.
// Geometry: grid (8,64)=512 blocks, 256 thr, 2 blocks/CU (64KB LDS), per-thread
// 16 rows x 4 cols x 16 k. VGPR ~165 < 256 cap: no spill (R2/R6 were spill traps).

#define BATCH 1024
#define IN    256
#define OUT   512

__global__ __launch_bounds__(256, 2) void product_kernel(
    const float* __restrict__ x, const float* __restrict__ w,
    const float* __restrict__ bias, float* __restrict__ out)
{
    __shared__ float4 ws4[64 * 64];   // 64 KB: w rows o0..o0+63, phys chunk = c ^ ((row>>2)&7)

    const int tid  = threadIdx.x;
    const int wid  = tid >> 6;        // wave 0..3
    const int lane = tid & 63;
    const int sbl  = lane >> 4;       // in-wave k-split 0..3
    const int l4   = lane & 15;       // col group: cols o0 + 4*l4 .. +3
    const int s    = wid * 4 + sbl;   // k-split 0..15: chunks [4s, 4s+4)

    const int o0 = blockIdx.x * 64;
    const int b0 = blockIdx.y * 16;

    const float4* x4g = (const float4*)x;   // [1024][64]
    const float4* w4g = (const float4*)w;   // [512][64]

    // ---- stage w tile only: 64 rows x 64 chunks; wave writes whole rows
    //      (lane==chunk -> phys = lane ^ const = permutation, conflict-free) ----
    #pragma unroll
    for (int it = 0; it < 16; ++it) {
        const int r = it * 4 + wid;                         // 0..63, wave-uniform
        ws4[r * 64 + (lane ^ ((r >> 2) & 7))] = w4g[(o0 + r) * 64 + lane];
    }
    __syncthreads();

    // ---- main: 4 chunks (16 k) per thread over 16 rows x 4 cols ----
    float4 acc[16];
    #pragma unroll
    for (int i = 0; i < 16; ++i) acc[i] = make_float4(1.0f, 1.0f, 1.0f, 1.0f);

    const int wsw = l4 & 7;           // ws swizzle for rows 4*l4+j (row>>2 == l4)
    const int wr  = 4 * l4 * 64;      // base chunk of lane's 4 w rows

    #pragma unroll 1                  // one chunk-generation live at a time
    for (int p = 0; p < 4; ++p) {
        const int c = 4 * s + p;      // logical chunk for this thread

        // x chunks straight from global (L2-hot; 16-lane broadcast groups,
        // 16 independent loads in flight -> latency hidden under 512 VALU cyc)
        float4 xv[16];
        #pragma unroll
        for (int i = 0; i < 16; ++i) xv[i] = x4g[(size_t)(b0 + i) * 64 + c];

        const int cw = c ^ wsw;
        const float4 wv0 = ws4[wr + 0 * 64 + cw];
        const float4 wv1 = ws4[wr + 1 * 64 + cw];
        const float4 wv2 = ws4[wr + 2 * 64 + cw];
        const float4 wv3 = ws4[wr + 3 * 64 + cw];

        #pragma unroll
        for (int i = 0; i < 16; ++i) {
            acc[i].x *= __builtin_fmaf(xv[i].x, wv0.x, 1.0f);
            acc[i].y *= __builtin_fmaf(xv[i].x, wv1.x, 1.0f);
            acc[i].z *= __builtin_fmaf(xv[i].x, wv2.x, 1.0f);
            acc[i].w *= __builtin_fmaf(xv[i].x, wv3.x, 1.0f);
            acc[i].x *= __builtin_fmaf(xv[i].y, wv0.y, 1.0f);
            acc[i].y *= __builtin_fmaf(xv[i].y, wv1.y, 1.0f);
            acc[i].z *= __builtin_fmaf(xv[i].y, wv2.y, 1.0f);
            acc[i].w *= __builtin_fmaf(xv[i].y, wv3.y, 1.0f);
            acc[i].x *= __builtin_fmaf(xv[i].z, wv0.z, 1.0f);
            acc[i].y *= __builtin_fmaf(xv[i].z, wv1.z, 1.0f);
            acc[i].z *= __builtin_fmaf(xv[i].z, wv2.z, 1.0f);
            acc[i].w *= __builtin_fmaf(xv[i].z, wv3.z, 1.0f);
            acc[i].x *= __builtin_fmaf(xv[i].w, wv0.w, 1.0f);
            acc[i].y *= __builtin_fmaf(xv[i].w, wv1.w, 1.0f);
            acc[i].z *= __builtin_fmaf(xv[i].w, wv2.w, 1.0f);
            acc[i].w *= __builtin_fmaf(xv[i].w, wv3.w, 1.0f);
        }
    }

    // ---- combine: partials -> LDS (aliases ws4; all wv reads done), fixed order ----
    __syncthreads();
    float4* part4 = (float4*)ws4;     // [16 s][16 r][16 c4] float4 = 64 KB exactly
    #pragma unroll
    for (int i = 0; i < 16; ++i)
        part4[(s * 16 + i) * 16 + l4] = acc[i];
    __syncthreads();

    // ---- epilogue: thread -> (row r, col-group c4); prod over s; -1 + bias ----
    const int r  = tid >> 4;          // 0..15
    const int c4 = tid & 15;          // 0..15
    float4 pr = part4[r * 16 + c4];   // s = 0
    #pragma unroll
    for (int ss = 1; ss < 16; ++ss) {
        const float4 q = part4[(ss * 16 + r) * 16 + c4];
        pr.x *= q.x; pr.y *= q.y; pr.z *= q.z; pr.w *= q.w;
    }
    const float4 bv = ((const float4*)bias)[(o0 >> 2) + c4];
    float4 o;
    o.x = pr.x - 1.0f + bv.x;
    o.y = pr.y - 1.0f + bv.y;
    o.z = pr.z - 1.0f + bv.z;
    o.w = pr.w - 1.0f + bv.w;
    ((float4*)out)[(size_t)(b0 + r) * (OUT / 4) + (o0 >> 2) + c4] = o;
}

extern "C" void kernel_launch(void* const* d_in, const int* in_sizes, int n_in,
                              void* d_out, int out_size, void* d_ws, size_t ws_size,
                              hipStream_t stream) {
    const float* x    = (const float*)d_in[0];   // (1024, 256)
    const float* wgt  = (const float*)d_in[1];   // (512, 256)
    const float* bias = (const float*)d_in[2];   // (512,)
    float* out        = (float*)d_out;           // (1024, 512)

    dim3 grid(OUT / 64, BATCH / 16);   // (8, 64) = 512 blocks
    dim3 block(256);
    product_kernel<<<grid, block, 0, stream>>>(x, wgt, bias, out);
}